// Round 16
// baseline (427.054 us; speedup 1.0000x reference)
//
#include <hip/hip_runtime.h>
#include <hip/hip_fp16.h>
#include <math.h>

#define NN 100000
#define NE 1200000
#define DD 64
#define STRIDE 64   // ELL row stride; P(Poisson(12) >= 64) ~ 1e-28, guarded anyway

typedef _Float16 h16;

__device__ __forceinline__ float bcast_lane(float v, int k) {
  return __uint_as_float(__builtin_amdgcn_readlane(__float_as_uint(v), (unsigned)k));
}

// ---- fused degree-count + ELL bucket build ----
// WALL (measured r2/r8/r9): 2.4M device-scope scattered atomics ~25G/s;
// invariant to MLP depth (r9 4x null) and occupancy. 4 VGPRs, max residency,
// SEPARATE kernel (r5/r7: any fusion taxes build-block residency and loses).
__global__ __launch_bounds__(256) void k_build(const int* __restrict__ src,
                                               const int* __restrict__ dst,
                                               int* __restrict__ out_deg,
                                               int* __restrict__ cursor,
                                               int* __restrict__ ell) {
  int e = blockIdx.x * blockDim.x + threadIdx.x;
  if (e < NE) {
    int s = src[e];
    int d = dst[e];
    atomicAdd(&out_deg[s], 1);
    int p = atomicAdd(&cursor[d], 1);
    if (p < STRIDE) ell[(size_t)d * STRIDE + p] = s;   // never corrupt
  }
}

// ---- g0 = (feat * rsqrt(outdeg)) @ W0 -> fp16 rows (128 B) ----
__global__ __launch_bounds__(256) void k_gemm0(const float* __restrict__ x,
                                               const int* __restrict__ out_deg,
                                               const float* __restrict__ W,
                                               h16* __restrict__ g) {
  const int lane = threadIdx.x & 63;
  const int wave = (blockIdx.x * blockDim.x + threadIdx.x) >> 6;
  const int nw = (gridDim.x * blockDim.x) >> 6;
  float w[DD];
#pragma unroll
  for (int k = 0; k < DD; ++k) w[k] = W[k * DD + lane];
  for (int r = wave; r < NN; r += nw) {
    const float on = rsqrtf(fmaxf((float)out_deg[r], 1.0f));
    float xr = x[(size_t)r * DD + lane] * on;
    float acc = 0.0f;
#pragma unroll
    for (int k = 0; k < DD; ++k) acc = fmaf(__shfl(xr, k), w[k], acc);
    g[(size_t)r * DD + lane] = (h16)acc;
  }
}

// ---- agg, oct-gather form: 8 rows per vmem instruction, UNROLLED ----
// Request-wall probe (r12's loop variant collapsed MLP; this is the unrolled
// fix). lane l: edge slot o=l>>3, feat group f=l&7 (int4 = feats 8f..8f+7).
// 4 col loads + 4 row gathers, all 8 independent, cover 32 edges
// (P(deg>32) ~ 4e-7; rare tail loop for the rest). Cross-oct shfl_xor
// reduce; per-lane predication BEFORE accumulate; indices clamped BEFORE
// address formation (ELL slots past deg are uninitialized). Norms inline
// from degree counts. Epilogue gemm: W_next in LDS, readlane broadcast
// (feat 8*k2+c lives in lane k2, slot c).
template <bool LAST>
__global__ __launch_bounds__(256) void k_agg_oct(const h16* __restrict__ g,
                                                 const int* __restrict__ ell,
                                                 const int* __restrict__ indeg,
                                                 const int* __restrict__ outdeg,
                                                 const float* __restrict__ bias,
                                                 const float* __restrict__ Wn,
                                                 h16* __restrict__ out_h,
                                                 float* __restrict__ out_f) {
  __shared__ float Wl[DD * DD];
  if (!LAST) {
    for (int i = threadIdx.x; i < DD * DD; i += 256) Wl[i] = Wn[i];
    __syncthreads();
  }
  const int lane = threadIdx.x & 63;
  const int o = lane >> 3;       // edge slot 0..7
  const int f = lane & 7;        // feat group: feats 8f..8f+7
  const int wv = (blockIdx.x * 256 + threadIdx.x) >> 6;
  const int nw = (gridDim.x * 256) >> 6;
  const float4 bl0 = *(const float4*)(bias + f * 8);
  const float4 bl1 = *(const float4*)(bias + f * 8 + 4);
  for (int v = wv; v < NN; v += nw) {
    const int dg = indeg[v];
    const int deg = min(dg, STRIDE);
    const int* row = ell + (size_t)v * STRIDE;
    float a0 = 0, a1 = 0, a2 = 0, a3 = 0, a4 = 0, a5 = 0, a6 = 0, a7 = 0;
    if (deg > 0) {
      const int last = deg - 1;
      // 4 independent col loads (8 distinct addrs each)
      const int c0 = row[min(o, last)];
      const int c1 = row[min(8 + o, last)];
      const int c2 = row[min(16 + o, last)];
      const int c3 = row[min(24 + o, last)];
      union U { int4 v4; h16 h[8]; };
      // 4 independent row gathers, 8 rows (128-B lines) per instruction
      U u0, u1, u2, u3;
      u0.v4 = *(const int4*)(g + (size_t)c0 * DD + f * 8);
      u1.v4 = *(const int4*)(g + (size_t)c1 * DD + f * 8);
      u2.v4 = *(const int4*)(g + (size_t)c2 * DD + f * 8);
      u3.v4 = *(const int4*)(g + (size_t)c3 * DD + f * 8);
      if (o < deg) {
        a0 += (float)u0.h[0]; a1 += (float)u0.h[1]; a2 += (float)u0.h[2];
        a3 += (float)u0.h[3]; a4 += (float)u0.h[4]; a5 += (float)u0.h[5];
        a6 += (float)u0.h[6]; a7 += (float)u0.h[7];
      }
      if (8 + o < deg) {
        a0 += (float)u1.h[0]; a1 += (float)u1.h[1]; a2 += (float)u1.h[2];
        a3 += (float)u1.h[3]; a4 += (float)u1.h[4]; a5 += (float)u1.h[5];
        a6 += (float)u1.h[6]; a7 += (float)u1.h[7];
      }
      if (16 + o < deg) {
        a0 += (float)u2.h[0]; a1 += (float)u2.h[1]; a2 += (float)u2.h[2];
        a3 += (float)u2.h[3]; a4 += (float)u2.h[4]; a5 += (float)u2.h[5];
        a6 += (float)u2.h[6]; a7 += (float)u2.h[7];
      }
      if (24 + o < deg) {
        a0 += (float)u3.h[0]; a1 += (float)u3.h[1]; a2 += (float)u3.h[2];
        a3 += (float)u3.h[3]; a4 += (float)u3.h[4]; a5 += (float)u3.h[5];
        a6 += (float)u3.h[6]; a7 += (float)u3.h[7];
      }
      // rare tail (P(deg>32) ~ 4e-7 per node)
      for (int j = 32; j < deg; j += 8) {
        const int ci = row[min(j + o, last)];
        U u; u.v4 = *(const int4*)(g + (size_t)ci * DD + f * 8);
        if (j + o < deg) {
          a0 += (float)u.h[0]; a1 += (float)u.h[1]; a2 += (float)u.h[2];
          a3 += (float)u.h[3]; a4 += (float)u.h[4]; a5 += (float)u.h[5];
          a6 += (float)u.h[6]; a7 += (float)u.h[7];
        }
      }
    }
    // reduce across the 8 edge slots (lane bits 3..5)
#pragma unroll
    for (int m = 8; m <= 32; m <<= 1) {
      a0 += __shfl_xor(a0, m); a1 += __shfl_xor(a1, m);
      a2 += __shfl_xor(a2, m); a3 += __shfl_xor(a3, m);
      a4 += __shfl_xor(a4, m); a5 += __shfl_xor(a5, m);
      a6 += __shfl_xor(a6, m); a7 += __shfl_xor(a7, m);
    }
    const float inn = rsqrtf(fmaxf((float)dg, 1.0f));
    float x0 = fmaf(a0, inn, bl0.x), x1 = fmaf(a1, inn, bl0.y);
    float x2 = fmaf(a2, inn, bl0.z), x3 = fmaf(a3, inn, bl0.w);
    float x4 = fmaf(a4, inn, bl1.x), x5 = fmaf(a5, inn, bl1.y);
    float x6 = fmaf(a6, inn, bl1.z), x7 = fmaf(a7, inn, bl1.w);
    x0 = (x0 > 0.f) ? x0 : expm1f(x0); x1 = (x1 > 0.f) ? x1 : expm1f(x1);
    x2 = (x2 > 0.f) ? x2 : expm1f(x2); x3 = (x3 > 0.f) ? x3 : expm1f(x3);
    x4 = (x4 > 0.f) ? x4 : expm1f(x4); x5 = (x5 > 0.f) ? x5 : expm1f(x5);
    x6 = (x6 > 0.f) ? x6 : expm1f(x6); x7 = (x7 > 0.f) ? x7 : expm1f(x7);
    if (LAST) {
      if (lane < 8) {   // lanes 0..7 hold the full row (others replicate)
        float4 s0 = {x0, x1, x2, x3};
        float4 s1 = {x4, x5, x6, x7};
        *(float4*)(out_f + (size_t)v * DD + f * 8) = s0;
        *(float4*)(out_f + (size_t)v * DD + f * 8 + 4) = s1;
      }
    } else {
      const float on = rsqrtf(fmaxf((float)outdeg[v], 1.0f));
      const float y0 = x0 * on, y1 = x1 * on, y2 = x2 * on, y3 = x3 * on;
      const float y4 = x4 * on, y5 = x5 * on, y6 = x6 * on, y7 = x7 * on;
      float acc2 = 0.0f;
#pragma unroll
      for (int k2 = 0; k2 < 8; ++k2) {
        acc2 = fmaf(bcast_lane(y0, k2), Wl[(k2 * 8 + 0) * DD + lane], acc2);
        acc2 = fmaf(bcast_lane(y1, k2), Wl[(k2 * 8 + 1) * DD + lane], acc2);
        acc2 = fmaf(bcast_lane(y2, k2), Wl[(k2 * 8 + 2) * DD + lane], acc2);
        acc2 = fmaf(bcast_lane(y3, k2), Wl[(k2 * 8 + 3) * DD + lane], acc2);
        acc2 = fmaf(bcast_lane(y4, k2), Wl[(k2 * 8 + 4) * DD + lane], acc2);
        acc2 = fmaf(bcast_lane(y5, k2), Wl[(k2 * 8 + 5) * DD + lane], acc2);
        acc2 = fmaf(bcast_lane(y6, k2), Wl[(k2 * 8 + 6) * DD + lane], acc2);
        acc2 = fmaf(bcast_lane(y7, k2), Wl[(k2 * 8 + 7) * DD + lane], acc2);
      }
      out_h[(size_t)v * DD + lane] = (h16)acc2;
    }
  }
}

extern "C" void kernel_launch(void* const* d_in, const int* in_sizes, int n_in,
                              void* d_out, int out_size, void* d_ws, size_t ws_size,
                              hipStream_t stream) {
  (void)in_sizes; (void)n_in; (void)out_size; (void)ws_size;
  const float* feat = (const float*)d_in[0];
  const float* W0 = (const float*)d_in[1];
  const float* b0 = (const float*)d_in[2];
  const float* W1 = (const float*)d_in[3];
  const float* b1 = (const float*)d_in[4];
  const float* W2 = (const float*)d_in[5];
  const float* b2 = (const float*)d_in[6];
  const int* src = (const int*)d_in[7];
  const int* dst = (const int*)d_in[8];
  float* out = (float*)d_out;

  // workspace layout (~52 MB)
  char* p = (char*)d_ws;
  int* out_deg = (int*)p;      p += (size_t)NN * 4;   // }
  int* cursor  = (int*)p;      p += (size_t)NN * 4;   // } one contiguous memset
  int* ell  = (int*)p;         p += (size_t)NN * STRIDE * 4;   // 25.6 MB
  h16* gA   = (h16*)p;         p += (size_t)NN * DD * 2;       // 12.8 MB
  h16* gB   = (h16*)p;         p += (size_t)NN * DD * 2;       // 12.8 MB

  hipMemsetAsync(out_deg, 0, (size_t)NN * 2 * sizeof(int), stream);  // out_deg+cursor

  k_build<<<(NE + 255) / 256, 256, 0, stream>>>(src, dst, out_deg, cursor, ell);
  k_gemm0<<<1024, 256, 0, stream>>>(feat, out_deg, W0, gA);

  // layer 0: gather gA -> elu -> (*onorm) @ W1 => gB (fp16)
  k_agg_oct<false><<<2048, 256, 0, stream>>>(gA, ell, cursor, out_deg,
                                             b0, W1, gB, nullptr);
  // layer 1: gather gB -> elu -> (*onorm) @ W2 => gA (fp16)
  k_agg_oct<false><<<2048, 256, 0, stream>>>(gB, ell, cursor, out_deg,
                                             b1, W2, gA, nullptr);
  // layer 2: gather gA -> elu => final fp32 output
  k_agg_oct<true><<<2048, 256, 0, stream>>>(gA, ell, cursor, out_deg,
                                            b2, nullptr, nullptr, out);
}

// Round 17
// 377.488 us; speedup vs baseline: 1.1313x; 1.1313x over previous
//
#include <hip/hip_runtime.h>
#include <hip/hip_fp16.h>
#include <math.h>

#define NN 100000
#define NE 1200000
#define DD 64
#define STRIDE 64   // ELL row stride; P(Poisson(12) >= 64) ~ 1e-28, guarded anyway

typedef _Float16 h16;

__device__ __forceinline__ float bcast_lane(float v, int k) {
  return __uint_as_float(__builtin_amdgcn_readlane(__float_as_uint(v), (unsigned)k));
}

// ---- fused degree-count + ELL bucket build ----
// WALL (measured r2/r8/r9): 2.4M device-scope scattered atomics + 1.2M
// scattered stores ~30G ops/s; invariant to MLP depth (r9) and occupancy.
// 4 VGPRs, max residency, SEPARATE kernel (r5/r7: fusion taxes residency).
__global__ __launch_bounds__(256) void k_build(const int* __restrict__ src,
                                               const int* __restrict__ dst,
                                               int* __restrict__ out_deg,
                                               int* __restrict__ cursor,
                                               int* __restrict__ ell) {
  int e = blockIdx.x * blockDim.x + threadIdx.x;
  if (e < NE) {
    int s = src[e];
    int d = dst[e];
    atomicAdd(&out_deg[s], 1);
    int p = atomicAdd(&cursor[d], 1);
    if (p < STRIDE) ell[(size_t)d * STRIDE + p] = s;   // never corrupt
  }
}

// ---- g0 = (feat * rsqrt(outdeg)) @ W0 -> fp16 rows (128 B) ----
__global__ __launch_bounds__(256) void k_gemm0(const float* __restrict__ x,
                                               const int* __restrict__ out_deg,
                                               const float* __restrict__ W,
                                               h16* __restrict__ g) {
  const int lane = threadIdx.x & 63;
  const int wave = (blockIdx.x * blockDim.x + threadIdx.x) >> 6;
  const int nw = (gridDim.x * blockDim.x) >> 6;
  float w[DD];
#pragma unroll
  for (int k = 0; k < DD; ++k) w[k] = W[k * DD + lane];
  for (int r = wave; r < NN; r += nw) {
    const float on = rsqrtf(fmaxf((float)out_deg[r], 1.0f));
    float xr = x[(size_t)r * DD + lane] * on;
    float acc = 0.0f;
#pragma unroll
    for (int k = 0; k < DD; ++k) acc = fmaf(__shfl(xr, k), w[k], acc);
    g[(size_t)r * DD + lane] = (h16)acc;
  }
}

// ---- fused: z = inorm*sum_ELL g + b; x = elu(z); (non-last) (x*onorm)@Wn ----
// WALL (measured r10/r12/r13/r16): 1.2M random 128-B line fetches/layer at
// ~15.4G lines/s. Invariant to unroll width (r5), bytes/row (r9-fp16), and
// request count (r16-oct); panels (r11) and looped wide loads (r12) regress.
// This 16-edges/iter form is the best-measured shape. Norms inline from
// degree counts. Indices clamped BEFORE address formation (ELL slots past
// deg are uninitialized). Epilogue gemm: W_next in LDS, readlane broadcast,
// hidden under gather latency.
template <bool LAST>
__global__ __launch_bounds__(256) void k_agg_fused(const h16* __restrict__ g,
                                                   const int* __restrict__ ell,
                                                   const int* __restrict__ indeg,
                                                   const int* __restrict__ outdeg,
                                                   const float* __restrict__ bias,
                                                   const float* __restrict__ Wn,
                                                   h16* __restrict__ out_h,
                                                   float* __restrict__ out_f) {
  __shared__ float Wl[DD * DD];
  if (!LAST) {
    for (int i = threadIdx.x; i < DD * DD; i += 256) Wl[i] = Wn[i];
    __syncthreads();
  }
  const int lane = threadIdx.x & 63;
  const int wv = (blockIdx.x * 256 + threadIdx.x) >> 6;
  const int nw = (gridDim.x * 256) >> 6;
  const float b = bias[lane];
  for (int v = wv; v < NN; v += nw) {
    const int dg = indeg[v];
    const int deg = min(dg, STRIDE);
    const int* row = ell + (size_t)v * STRIDE;
    float acc = 0.0f;
    for (int j = 0; j < deg; j += 16) {
      const int4 c0 = *(const int4*)(row + j);
      const int4 c1 = *(const int4*)(row + j + 4);
      const int4 c2 = *(const int4*)(row + j + 8);
      const int4 c3 = *(const int4*)(row + j + 12);
      const int s0 = c0.x;                            // j < deg always
      const int s1 = (j + 1 < deg) ? c0.y : 0;
      const int s2 = (j + 2 < deg) ? c0.z : 0;
      const int s3 = (j + 3 < deg) ? c0.w : 0;
      const int s4 = (j + 4 < deg) ? c1.x : 0;
      const int s5 = (j + 5 < deg) ? c1.y : 0;
      const int s6 = (j + 6 < deg) ? c1.z : 0;
      const int s7 = (j + 7 < deg) ? c1.w : 0;
      const int s8 = (j + 8 < deg) ? c2.x : 0;
      const int s9 = (j + 9 < deg) ? c2.y : 0;
      const int sa = (j + 10 < deg) ? c2.z : 0;
      const int sb = (j + 11 < deg) ? c2.w : 0;
      const int sc = (j + 12 < deg) ? c3.x : 0;
      const int sd = (j + 13 < deg) ? c3.y : 0;
      const int se = (j + 14 < deg) ? c3.z : 0;
      const int sf = (j + 15 < deg) ? c3.w : 0;
      const float v0 = (float)g[(size_t)s0 * DD + lane];
      const float v1 = (float)g[(size_t)s1 * DD + lane];
      const float v2 = (float)g[(size_t)s2 * DD + lane];
      const float v3 = (float)g[(size_t)s3 * DD + lane];
      const float v4 = (float)g[(size_t)s4 * DD + lane];
      const float v5 = (float)g[(size_t)s5 * DD + lane];
      const float v6 = (float)g[(size_t)s6 * DD + lane];
      const float v7 = (float)g[(size_t)s7 * DD + lane];
      const float v8 = (float)g[(size_t)s8 * DD + lane];
      const float v9 = (float)g[(size_t)s9 * DD + lane];
      const float va = (float)g[(size_t)sa * DD + lane];
      const float vb = (float)g[(size_t)sb * DD + lane];
      const float vc = (float)g[(size_t)sc * DD + lane];
      const float vd = (float)g[(size_t)sd * DD + lane];
      const float ve = (float)g[(size_t)se * DD + lane];
      const float vf = (float)g[(size_t)sf * DD + lane];
      acc += v0;
      acc += (j + 1 < deg) ? v1 : 0.0f;
      acc += (j + 2 < deg) ? v2 : 0.0f;
      acc += (j + 3 < deg) ? v3 : 0.0f;
      acc += (j + 4 < deg) ? v4 : 0.0f;
      acc += (j + 5 < deg) ? v5 : 0.0f;
      acc += (j + 6 < deg) ? v6 : 0.0f;
      acc += (j + 7 < deg) ? v7 : 0.0f;
      acc += (j + 8 < deg) ? v8 : 0.0f;
      acc += (j + 9 < deg) ? v9 : 0.0f;
      acc += (j + 10 < deg) ? va : 0.0f;
      acc += (j + 11 < deg) ? vb : 0.0f;
      acc += (j + 12 < deg) ? vc : 0.0f;
      acc += (j + 13 < deg) ? vd : 0.0f;
      acc += (j + 14 < deg) ? ve : 0.0f;
      acc += (j + 15 < deg) ? vf : 0.0f;
    }
    const float inn = rsqrtf(fmaxf((float)dg, 1.0f));
    float z = fmaf(acc, inn, b);
    float x = (z > 0.0f) ? z : expm1f(z);
    if (LAST) {
      out_f[(size_t)v * DD + lane] = x;
    } else {
      const float on = rsqrtf(fmaxf((float)outdeg[v], 1.0f));
      float xs = x * on;
      float a2 = 0.0f;
#pragma unroll
      for (int k = 0; k < DD; ++k)
        a2 = fmaf(bcast_lane(xs, k), Wl[k * DD + lane], a2);
      out_h[(size_t)v * DD + lane] = (h16)a2;
    }
  }
}

extern "C" void kernel_launch(void* const* d_in, const int* in_sizes, int n_in,
                              void* d_out, int out_size, void* d_ws, size_t ws_size,
                              hipStream_t stream) {
  (void)in_sizes; (void)n_in; (void)out_size; (void)ws_size;
  const float* feat = (const float*)d_in[0];
  const float* W0 = (const float*)d_in[1];
  const float* b0 = (const float*)d_in[2];
  const float* W1 = (const float*)d_in[3];
  const float* b1 = (const float*)d_in[4];
  const float* W2 = (const float*)d_in[5];
  const float* b2 = (const float*)d_in[6];
  const int* src = (const int*)d_in[7];
  const int* dst = (const int*)d_in[8];
  float* out = (float*)d_out;

  // workspace layout (~52 MB)
  char* p = (char*)d_ws;
  int* out_deg = (int*)p;      p += (size_t)NN * 4;   // }
  int* cursor  = (int*)p;      p += (size_t)NN * 4;   // } one contiguous memset
  int* ell  = (int*)p;         p += (size_t)NN * STRIDE * 4;   // 25.6 MB
  h16* gA   = (h16*)p;         p += (size_t)NN * DD * 2;       // 12.8 MB
  h16* gB   = (h16*)p;         p += (size_t)NN * DD * 2;       // 12.8 MB

  hipMemsetAsync(out_deg, 0, (size_t)NN * 2 * sizeof(int), stream);  // out_deg+cursor

  k_build<<<(NE + 255) / 256, 256, 0, stream>>>(src, dst, out_deg, cursor, ell);
  k_gemm0<<<1024, 256, 0, stream>>>(feat, out_deg, W0, gA);

  // layer 0: gather gA -> elu -> (*onorm) @ W1 => gB (fp16)
  k_agg_fused<false><<<2048, 256, 0, stream>>>(gA, ell, cursor, out_deg,
                                               b0, W1, gB, nullptr);
  // layer 1: gather gB -> elu -> (*onorm) @ W2 => gA (fp16)
  k_agg_fused<false><<<2048, 256, 0, stream>>>(gB, ell, cursor, out_deg,
                                               b1, W2, gA, nullptr);
  // layer 2: gather gA -> elu => final fp32 output
  k_agg_fused<true><<<2048, 256, 0, stream>>>(gA, ell, cursor, out_deg,
                                              b2, nullptr, nullptr, out);
}